// Round 6
// baseline (520.829 us; speedup 1.0000x reference)
//
#include <hip/hip_runtime.h>
#include <hip/hip_fp16.h>
#include <math.h>

// Problem constants (match reference)
#define R_TOT 4096
#define L_LEN 128
#define D_DIM 200
#define A_DIM 20
#define NEGK  2
#define B_SZ  1024
#define NNZ_C 20480
#define RN_TOT (R_TOT*NEGK)
#define VOCAB_C 32000
#define EPS_ 1e-12f
#define SLOT_CAP 64          // Poisson(20) max bin ~45; 64 is safe
#define NBUCK_BLK 160        // 160*256 = 40960 = 2*NNZ_C

__device__ __forceinline__ float4 unpack4(const uint2 u) {
  union { unsigned v; __half2 h; } c0, c1;
  c0.v = u.x; c1.v = u.y;
  const float2 f0 = __half22float2(c0.h);
  const float2 f1 = __half22float2(c1.h);
  return make_float4(f0.x, f0.y, f1.x, f1.y);
}

// ---------------- K0: cast emb -> fp16 table; block 0 also zeroes bucket counters ----------------
__global__ __launch_bounds__(256) void k_cast(
    const float* __restrict__ emb, ushort* __restrict__ emb_h, int* __restrict__ cnt)
{
  if (blockIdx.x == 0) {
    for (int i = threadIdx.x; i < 2*B_SZ; i += 256) cnt[i] = 0;
  }
  const int idx = blockIdx.x*256 + threadIdx.x;
  if (idx < (VOCAB_C*D_DIM)/4) {
    const float4 v = reinterpret_cast<const float4*>(emb)[idx];
    ushort4 o;
    o.x = __half_as_ushort(__float2half(v.x));
    o.y = __half_as_ushort(__float2half(v.y));
    o.z = __half_as_ushort(__float2half(v.z));
    o.w = __half_as_ushort(__float2half(v.w));
    reinterpret_cast<ushort4*>(emb_h)[idx] = o;
  }
}

// ---------------- K1: FUSED per-review pipeline ----------------
// Stage e_w (fp16, 51.2 KB) into LDS once via 3200 independent uint4 loads,
// then y_s, v=Wm.y_s, dx, softmax, z_s, p_t, r_s, c1 all from LDS/L2.
// LDS ~55 KB -> 2 blocks/CU (8 waves); staging is bulk-MLP so latency hides.
__global__ __launch_bounds__(256, 2) void k_fused(
    const int* __restrict__ hist, const ushort* __restrict__ emb_h,
    const float* __restrict__ Wm, const float* __restrict__ Ww,
    const float* __restrict__ bw, const float* __restrict__ Wt,
    float* __restrict__ rs_out, float* __restrict__ c1_out,
    float* __restrict__ rsinv_out)
{
  __shared__ __align__(16) unsigned ew_u[12800];   // 128*200 halves; uint j = halves 2j,2j+1
  __shared__ int widx[L_LEN];
  __shared__ __align__(16) float ys[D_DIM];
  __shared__ __align__(16) float vv[D_DIM];
  __shared__ __align__(16) float ax[L_LEN];
  __shared__ float zs[D_DIM];
  __shared__ float ptile[160];
  __shared__ float red[40];
  const int r = blockIdx.x;
  const int tid = threadIdx.x, lane = tid & 63, wv = tid >> 6;

  if (tid < L_LEN) widx[tid] = hist[r*L_LEN + tid];
  __syncthreads();

  // ---- stage: 3200 x uint4 (16B = 8 halves); row = 25 chunks of 16B ----
  for (int i = tid; i < 3200; i += 256) {
    const int w = i / 25;
    const int c = i - 25*w;
    const uint4 v = *reinterpret_cast<const uint4*>(emb_h + (size_t)widx[w]*D_DIM + 8*c);
    *reinterpret_cast<uint4*>(&ew_u[i*4]) = v;
  }
  __syncthreads();

  // ---- y_s: column-pair sums; waves 0-1 rows 0..63 -> ys[], waves 2-3 rows 64..127 -> vv[] ----
  {
    const bool lo = (tid < 100), hi = (tid >= 128 && tid < 228);
    if (lo || hi) {
      const int p = lo ? tid : tid - 128;      // column pair p -> cols 2p, 2p+1
      const int l0 = lo ? 0 : 64;
      float sx = 0.f, sy = 0.f;
      #pragma unroll 8
      for (int l = l0; l < l0 + 64; ++l) {
        union { unsigned v; __half2 h; } cvt;
        cvt.v = ew_u[l*100 + p];
        const float2 f = __half22float2(cvt.h);
        sx += f.x; sy += f.y;
      }
      float* dst = lo ? ys : vv;
      dst[2*p] = sx; dst[2*p + 1] = sy;
    }
  }
  __syncthreads();
  if (tid < D_DIM) ys[tid] = (ys[tid] + vv[tid]) * (1.0f/128.0f);
  __syncthreads();

  // ---- v[d] = sum_k ys[k] * Wm[k*200+d]  (Wm coalesced, L2-hot) ----
  if (tid < D_DIM) {
    float s = 0.f;
    #pragma unroll 4
    for (int k = 0; k < D_DIM; ++k) s += ys[k] * Wm[k*D_DIM + tid];
    vv[tid] = s;
  }
  __syncthreads();

  // ---- dx[l] = e_w[l,:].v — wave-per-row from LDS, butterfly ----
  {
    float4 v4 = {0.f,0.f,0.f,0.f};
    if (lane < 50) v4 = *reinterpret_cast<const float4*>(vv + 4*lane);
    for (int l = wv; l < L_LEN; l += 4) {
      float a = 0.f;
      if (lane < 50) {
        const float4 e4 = unpack4(*reinterpret_cast<const uint2*>(&ew_u[l*100 + 2*lane]));
        a = e4.x*v4.x + e4.y*v4.y + e4.z*v4.z + e4.w*v4.w;
      }
      #pragma unroll
      for (int o = 32; o > 0; o >>= 1) a += __shfl_xor(a, o);
      if (lane == 0) ax[l] = a;
    }
  }
  __syncthreads();

  // ---- softmax over 128 (wave0 reduces) ----
  if (tid < 64) {
    float m = fmaxf(ax[tid], ax[tid+64]);
    #pragma unroll
    for (int o = 32; o > 0; o >>= 1) m = fmaxf(m, __shfl_xor(m, o));
    if (tid == 0) red[0] = m;
  }
  __syncthreads();
  const float M = red[0];
  if (tid < L_LEN) ax[tid] = expf(ax[tid] - M);
  __syncthreads();
  if (tid < 64) {
    float s = ax[tid] + ax[tid+64];
    #pragma unroll
    for (int o = 32; o > 0; o >>= 1) s += __shfl_xor(s, o);
    if (tid == 0) red[1] = s;
  }
  __syncthreads();
  const float Sinv = 1.0f / red[1];
  if (tid < L_LEN) ax[tid] *= Sinv;
  __syncthreads();

  // ---- z_s[d] = sum_i ax[i]*flat[128d+i]; flat half f -> uint f/2; half-wave per d ----
  {
    const int lh = lane & 31;
    const float4 ax4 = *reinterpret_cast<const float4*>(ax + 4*lh);
    for (int dp = wv; dp < 100; dp += 4) {
      const int d = 2*dp + (lane >> 5);
      const float4 e4 = unpack4(*reinterpret_cast<const uint2*>(&ew_u[64*d + 2*lh]));
      float a = e4.x*ax4.x + e4.y*ax4.y + e4.z*ax4.z + e4.w*ax4.w;
      #pragma unroll
      for (int o = 16; o > 0; o >>= 1) a += __shfl_xor(a, o);
      if (lh == 0) zs[d] = a;
    }
  }
  __syncthreads();

  // ---- p_t[a] = z_s . Ww[a,:] + bw[a]  — 8x20 partials ----
  if (tid < 160) {
    const int a = tid % 20, j = tid / 20;
    float s = 0.f;
    #pragma unroll
    for (int i = 0; i < 25; ++i) {
      const int d = j + 8*i;
      s += zs[d] * Ww[a*D_DIM + d];
    }
    ptile[tid] = s;
  }
  __syncthreads();
  if (tid < A_DIM) {
    float s = bw[tid];
    #pragma unroll
    for (int j = 0; j < 8; ++j) s += ptile[j*20 + tid];
    red[2 + tid] = s;
  }
  __syncthreads();

  // ---- r_s[d] = sum_a p_t[a]*Wt[d,a]; norms for c1 ----
  float rsd = 0.f, zsd = 0.f;
  if (tid < D_DIM) {
    float acc = 0.f;
    #pragma unroll
    for (int a = 0; a < A_DIM; ++a) acc += red[2+a] * Wt[tid*A_DIM + a];
    rsd = acc; zsd = zs[tid];
    rs_out[(size_t)r*D_DIM + tid] = acc;
  }
  float a0 = rsd*rsd, a1 = zsd*zsd, a2 = rsd*zsd;
  #pragma unroll
  for (int o = 32; o > 0; o >>= 1) {
    a0 += __shfl_xor(a0, o); a1 += __shfl_xor(a1, o); a2 += __shfl_xor(a2, o);
  }
  if ((tid & 63) == 0) { red[24+wv] = a0; red[28+wv] = a1; red[32+wv] = a2; }
  __syncthreads();
  if (tid == 0) {
    const float s0 = red[24]+red[25]+red[26]+red[27];
    const float s1 = red[28]+red[29]+red[30]+red[31];
    const float s2 = red[32]+red[33]+red[34]+red[35];
    const float nr = fmaxf(sqrtf(s0), EPS_);
    const float nz = fmaxf(sqrtf(s1), EPS_);
    c1_out[r] = s2 / (nr * nz);
    rsinv_out[r] = 1.0f / nr;
  }
}

// ---------------- K2: neg mean + c2 + margin loss fused; tail blocks do sparse bucketing ----------------
__global__ __launch_bounds__(256, 8) void k_neg(
    const int* __restrict__ neg, const ushort* __restrict__ emb_h,
    const float* __restrict__ rs, const float* __restrict__ c1,
    const float* __restrict__ rsinv, float* __restrict__ abae,
    const int* __restrict__ uidx, const float* __restrict__ uval,
    const int* __restrict__ iidx, const float* __restrict__ ival,
    int* __restrict__ cnt, int* __restrict__ scol, float* __restrict__ sval)
{
  const int s = blockIdx.x;
  const int tid = threadIdx.x, lane = tid & 63, wv = tid >> 6;

  if (s >= RN_TOT) {
    // ---- bucket pass: one thread per nnz entry (user then item) ----
    const int g = (s - RN_TOT)*256 + tid;
    if (g < NNZ_C) {
      const int b = uidx[g];
      const int slot = atomicAdd(&cnt[b], 1);
      if (slot < SLOT_CAP) {
        scol[b*SLOT_CAP + slot] = uidx[NNZ_C + g];
        sval[b*SLOT_CAP + slot] = uval[g];
      }
    } else {
      const int g2 = g - NNZ_C;
      const int b = iidx[g2];
      const int slot = atomicAdd(&cnt[B_SZ + b], 1);
      if (slot < SLOT_CAP) {
        scol[(B_SZ + b)*SLOT_CAP + slot] = iidx[NNZ_C + g2];
        sval[(B_SZ + b)*SLOT_CAP + slot] = ival[g2];
      }
    }
    return;
  }

  __shared__ int widx[L_LEN];
  __shared__ __align__(16) float part[4][D_DIM];
  __shared__ float red[8];
  const int rn = s;
  const int r = rn >> 1;               // NEG = 2
  if (tid < L_LEN) widx[tid] = neg[(size_t)rn*L_LEN + tid];
  __syncthreads();

  float4 acc = {0.f, 0.f, 0.f, 0.f};
  for (int l = wv; l < L_LEN; l += 4) {
    if (lane < 50) {
      const float4 v = unpack4(*reinterpret_cast<const uint2*>(
          emb_h + (size_t)widx[l]*D_DIM + 4*lane));
      acc.x += v.x; acc.y += v.y; acc.z += v.z; acc.w += v.w;
    }
  }
  if (lane < 50) *reinterpret_cast<float4*>(&part[wv][4*lane]) = acc;
  __syncthreads();

  // zn[tid] + dot with rs[r]; butterfly + cross-wave combine
  float zn = 0.f, rsd = 0.f;
  if (tid < D_DIM) {
    zn = (part[0][tid] + part[1][tid] + part[2][tid] + part[3][tid]) * (1.0f/128.0f);
    rsd = rs[(size_t)r*D_DIM + tid];
  }
  float a0 = zn*zn, a1 = zn*rsd;
  #pragma unroll
  for (int o = 32; o > 0; o >>= 1) { a0 += __shfl_xor(a0,o); a1 += __shfl_xor(a1,o); }
  if ((tid & 63) == 0) { red[wv] = a0; red[4+wv] = a1; }
  __syncthreads();
  if (tid == 0) {
    const float s0 = red[0]+red[1]+red[2]+red[3];
    const float s1 = red[4]+red[5]+red[6]+red[7];
    const float nz = fmaxf(sqrtf(s0), EPS_);
    abae[rn] = fmaxf((s1/nz)*rsinv[r] - c1[r] + 1.0f, 0.0f);
  }
}

// ---------------- K3: segment-sum apply from bucket lists ----------------
__global__ __launch_bounds__(256) void k_agg2(
    const int* __restrict__ cnt, const int* __restrict__ scol,
    const float* __restrict__ sval, const float* __restrict__ rs,
    float* __restrict__ uae, float* __restrict__ iae)
{
  const int seg = blockIdx.x;            // 0..2047: user then item
  const int b = seg & (B_SZ - 1);
  float* outp = ((seg < B_SZ) ? uae : iae) + (size_t)b*D_DIM;
  int n = cnt[seg];
  n = n < SLOT_CAP ? n : SLOT_CAP;
  const int* cols = scol + (size_t)seg*SLOT_CAP;
  const float* vals = sval + (size_t)seg*SLOT_CAP;
  if (threadIdx.x < D_DIM) {
    float acc = 0.f;
    for (int j = 0; j < n; ++j)
      acc += vals[j] * rs[(size_t)cols[j]*D_DIM + threadIdx.x];
    outp[threadIdx.x] = acc;
  }
}

// ---------------- K4: FM per-b linear term + per-b quadratic partial ----------------
__global__ __launch_bounds__(64) void k_fm1(
    const float* __restrict__ uae, const float* __restrict__ iae,
    const float* __restrict__ fcw, const float* __restrict__ V,
    float* __restrict__ linb, float* __restrict__ quadb)
{
  const int b = blockIdx.x;
  const int lane = threadIdx.x;
  float iv[7];
  #pragma unroll
  for (int j = 0; j < 7; ++j) {
    const int f = lane + 64*j;
    float v = 0.f;
    if (f < D_DIM) v = uae[(size_t)b*D_DIM + f];
    else if (f < 2*D_DIM) v = iae[(size_t)b*D_DIM + f - D_DIM];
    iv[j] = v;
  }
  float lin = 0.f;
  #pragma unroll
  for (int j = 0; j < 7; ++j) {
    const int f = lane + 64*j;
    if (f < 2*D_DIM) lin += iv[j]*fcw[f];
  }
  float quad = 0.f;
  for (int k = 0; k < 10; ++k) {
    float s1 = 0.f, s2 = 0.f;
    #pragma unroll
    for (int j = 0; j < 7; ++j) {
      const int f = lane + 64*j;
      if (f < 2*D_DIM) {
        const float vk = V[f*10 + k];
        s1 += iv[j]*vk;
        s2 += iv[j]*iv[j]*vk*vk;
      }
    }
    #pragma unroll
    for (int o = 32; o > 0; o >>= 1) { s1 += __shfl_xor(s1,o); s2 += __shfl_xor(s2,o); }
    quad += s1*s1 - s2;
  }
  #pragma unroll
  for (int o = 32; o > 0; o >>= 1) lin += __shfl_xor(lin,o);
  if (lane == 0) { linb[b] = lin; quadb[b] = quad; }
}

// ---------------- K5: fused quad-reduce + prediction + all final scalars ----------------
__global__ __launch_bounds__(1024) void k_final2(
    const float* __restrict__ quadb, const float* __restrict__ linb,
    const float* __restrict__ fcb, const int* __restrict__ user,
    const int* __restrict__ item, const float* __restrict__ busers,
    const float* __restrict__ bitems, const float* __restrict__ label,
    const float* __restrict__ Wt, const float* __restrict__ abae,
    float* __restrict__ pred, float* __restrict__ rl, float* __restrict__ obj)
{
  __shared__ float sA[16], sB[16], sC[16];
  __shared__ float cninv[A_DIM];
  __shared__ float quad_s;
  const int tid = threadIdx.x;
  const int lane = tid & 63;
  const int wv = tid >> 6;

  float q = quadb[tid];
  #pragma unroll
  for (int o = 32; o > 0; o >>= 1) q += __shfl_xor(q, o);
  if (lane == 0) sA[wv] = q;

  if (tid < A_DIM) {
    float s = 0.f;
    for (int d = 0; d < D_DIM; ++d) { const float w = Wt[d*A_DIM + tid]; s += w*w; }
    cninv[tid] = 1.0f / fmaxf(sqrtf(s), EPS_);
  }
  __syncthreads();
  if (wv == 0) {
    float s = (lane < 16) ? sA[lane] : 0.f;
    #pragma unroll
    for (int o = 32; o > 0; o >>= 1) s += __shfl_xor(s, o);
    if (lane == 0) quad_s = s;
  }
  __syncthreads();

  const float p = 0.5f*quad_s + linb[tid] + fcb[0]
                + busers[user[tid]] + bitems[item[tid]];
  pred[tid] = p;
  const float dd = p - label[tid];
  const float myrl = dd*dd;
  rl[tid] = myrl;

  float u = 0.f;
  if (tid < 400) {
    const int a = tid / 20, c = tid % 20;
    float dot = 0.f;
    for (int d = 0; d < D_DIM; ++d) dot += Wt[d*A_DIM + a]*Wt[d*A_DIM + c];
    const float g = dot*cninv[a]*cninv[c] - (a==c ? 1.0f : 0.0f);
    u = g*g;
  }
  float js = 0.f;
  #pragma unroll
  for (int j = 0; j < 8; ++j) js += abae[tid + 1024*j];
  float ms = myrl;

  #pragma unroll
  for (int o = 32; o > 0; o >>= 1) {
    u += __shfl_xor(u,o); js += __shfl_xor(js,o); ms += __shfl_xor(ms,o);
  }
  if (lane == 0) { sA[wv] = u; sB[wv] = js; sC[wv] = ms; }
  __syncthreads();
  if (tid == 0) {
    float U = 0.f, J = 0.f, Ms = 0.f;
    for (int i = 0; i < 16; ++i) { U += sA[i]; J += sB[i]; Ms += sC[i]; }
    obj[0] = Ms/1024.0f + 0.01f*(J/8192.0f) + 0.01f*(U/400.0f);
  }
}

extern "C" void kernel_launch(void* const* d_in, const int* in_sizes, int n_in,
                              void* d_out, int out_size, void* d_ws, size_t ws_size,
                              hipStream_t stream) {
  const int*   hist   = (const int*)  d_in[0];
  const int*   neg    = (const int*)  d_in[1];
  const int*   user   = (const int*)  d_in[2];
  const int*   item   = (const int*)  d_in[3];
  const float* label  = (const float*)d_in[4];
  const int*   uidx   = (const int*)  d_in[5];
  const float* uval   = (const float*)d_in[6];
  const int*   iidx   = (const int*)  d_in[7];
  const float* ival   = (const float*)d_in[8];
  const float* emb    = (const float*)d_in[9];
  const float* Wm     = (const float*)d_in[10];
  const float* Ww     = (const float*)d_in[11];
  const float* bw     = (const float*)d_in[12];
  const float* Wt     = (const float*)d_in[13];
  const float* fcw    = (const float*)d_in[14];
  const float* fcb    = (const float*)d_in[15];
  const float* V      = (const float*)d_in[16];
  const float* busers = (const float*)d_in[17];
  const float* bitems = (const float*)d_in[18];

  float* out  = (float*)d_out;
  float* obj  = out;                       // 1
  float* rl   = out + 1;                   // 1024
  float* abae = out + 1 + B_SZ;            // 8192
  float* pred = out + 1 + B_SZ + RN_TOT;   // 1024
  float* uae  = pred + B_SZ;               // 204800
  float* iae  = uae + (size_t)B_SZ*D_DIM;  // 204800

  float* ws     = (float*)d_ws;
  float* rs     = ws;                              // R*D
  float* c1     = rs + (size_t)R_TOT*D_DIM;        // R
  float* rsinv  = c1 + R_TOT;                      // R
  float* linb   = rsinv + R_TOT;                   // B
  float* quadb  = linb + B_SZ;                     // B
  float* sval   = quadb + B_SZ;                    // 2*B*SLOT_CAP floats
  int*   scol   = (int*)(sval + (size_t)2*B_SZ*SLOT_CAP);   // 2*B*SLOT_CAP ints
  int*   cnt    = scol + (size_t)2*B_SZ*SLOT_CAP;           // 2*B ints
  ushort* emb_h = (ushort*)(cnt + 2*B_SZ);                  // VOCAB*D halves

  const int cast_blocks = (VOCAB_C*D_DIM/4 + 255)/256;      // 6250

  k_cast  <<<cast_blocks, 256, 0, stream>>>(emb, emb_h, cnt);
  k_fused <<<R_TOT, 256, 0, stream>>>(hist, emb_h, Wm, Ww, bw, Wt, rs, c1, rsinv);
  k_neg   <<<RN_TOT + NBUCK_BLK, 256, 0, stream>>>(neg, emb_h, rs, c1, rsinv, abae,
                                                   uidx, uval, iidx, ival,
                                                   cnt, scol, sval);
  k_agg2  <<<2*B_SZ, 256, 0, stream>>>(cnt, scol, sval, rs, uae, iae);
  k_fm1   <<<B_SZ, 64, 0, stream>>>(uae, iae, fcw, V, linb, quadb);
  k_final2<<<1, 1024, 0, stream>>>(quadb, linb, fcb, user, item, busers, bitems,
                                   label, Wt, abae, pred, rl, obj);
}

// Round 7
// 438.537 us; speedup vs baseline: 1.1877x; 1.1877x over previous
//
#include <hip/hip_runtime.h>
#include <hip/hip_fp16.h>
#include <math.h>

// Problem constants (match reference)
#define R_TOT 4096
#define L_LEN 128
#define D_DIM 200
#define A_DIM 20
#define NEGK  2
#define B_SZ  1024
#define NNZ_C 20480
#define RN_TOT (R_TOT*NEGK)
#define VOCAB_C 32000
#define EPS_ 1e-12f
#define SLOT_CAP 64          // Poisson(20) max bin ~45; 64 is safe
#define NBUCK_BLK 160        // 160*256 = 40960 = 2*NNZ_C

__device__ __forceinline__ float4 unpack4(const uint2 u) {
  union { unsigned v; __half2 h; } c0, c1;
  c0.v = u.x; c1.v = u.y;
  const float2 f0 = __half22float2(c0.h);
  const float2 f1 = __half22float2(c1.h);
  return make_float4(f0.x, f0.y, f1.x, f1.y);
}

// ---------------- K0: cast emb -> fp16 table; block 0 also zeroes bucket counters ----------------
__global__ __launch_bounds__(256) void k_cast(
    const float* __restrict__ emb, ushort* __restrict__ emb_h, int* __restrict__ cnt)
{
  if (blockIdx.x == 0) {
    for (int i = threadIdx.x; i < 2*B_SZ; i += 256) cnt[i] = 0;
  }
  const int idx = blockIdx.x*256 + threadIdx.x;
  if (idx < (VOCAB_C*D_DIM)/4) {
    const float4 v = reinterpret_cast<const float4*>(emb)[idx];
    ushort4 o;
    o.x = __half_as_ushort(__float2half(v.x));
    o.y = __half_as_ushort(__float2half(v.y));
    o.z = __half_as_ushort(__float2half(v.z));
    o.w = __half_as_ushort(__float2half(v.w));
    reinterpret_cast<ushort4*>(emb_h)[idx] = o;
  }
}

// ---------------- K1: pos means, ILP-4 unrolled gathers ----------------
__global__ __launch_bounds__(256, 8) void k_pos_mean(
    const int* __restrict__ hist, const ushort* __restrict__ emb_h,
    float* __restrict__ ys_all)
{
  __shared__ int widx[L_LEN];
  __shared__ __align__(16) float part[4][D_DIM];
  const int r = blockIdx.x;
  const int tid = threadIdx.x, lane = tid & 63, wv = tid >> 6;
  if (tid < L_LEN) widx[tid] = hist[(size_t)r*L_LEN + tid];
  __syncthreads();
  float4 a0 = {0,0,0,0}, a1 = {0,0,0,0}, a2 = {0,0,0,0}, a3 = {0,0,0,0};
  if (lane < 50) {
    const int l0 = wv*32;
    #pragma unroll
    for (int g = 0; g < 8; ++g) {
      const int l = l0 + g*4;
      const float4 v0 = unpack4(*reinterpret_cast<const uint2*>(emb_h + (size_t)widx[l  ]*D_DIM + 4*lane));
      const float4 v1 = unpack4(*reinterpret_cast<const uint2*>(emb_h + (size_t)widx[l+1]*D_DIM + 4*lane));
      const float4 v2 = unpack4(*reinterpret_cast<const uint2*>(emb_h + (size_t)widx[l+2]*D_DIM + 4*lane));
      const float4 v3 = unpack4(*reinterpret_cast<const uint2*>(emb_h + (size_t)widx[l+3]*D_DIM + 4*lane));
      a0.x += v0.x; a0.y += v0.y; a0.z += v0.z; a0.w += v0.w;
      a1.x += v1.x; a1.y += v1.y; a1.z += v1.z; a1.w += v1.w;
      a2.x += v2.x; a2.y += v2.y; a2.z += v2.z; a2.w += v2.w;
      a3.x += v3.x; a3.y += v3.y; a3.z += v3.z; a3.w += v3.w;
    }
    a0.x += a1.x + a2.x + a3.x; a0.y += a1.y + a2.y + a3.y;
    a0.z += a1.z + a2.z + a3.z; a0.w += a1.w + a2.w + a3.w;
    *reinterpret_cast<float4*>(&part[wv][4*lane]) = a0;
  }
  __syncthreads();
  if (tid < D_DIM)
    ys_all[(size_t)r*D_DIM + tid] =
        (part[0][tid] + part[1][tid] + part[2][tid] + part[3][tid]) * (1.0f/128.0f);
}

// ---------------- K2: V = Y @ Wm (16 reviews/block) ----------------
#define KB_RT 16
__global__ __launch_bounds__(256, 2) void k_matvec(
    const float* __restrict__ ys_all, const float* __restrict__ Wm,
    float* __restrict__ vv_all)
{
  __shared__ float ysl[KB_RT][D_DIM];
  const int r0 = blockIdx.x * KB_RT;
  const int tid = threadIdx.x;
  for (int i = tid; i < KB_RT*D_DIM; i += 256)
    ysl[i / D_DIM][i % D_DIM] = ys_all[(size_t)r0*D_DIM + i];
  __syncthreads();
  if (tid < D_DIM) {
    float acc[KB_RT];
    #pragma unroll
    for (int r = 0; r < KB_RT; ++r) acc[r] = 0.f;
    #pragma unroll 4
    for (int k = 0; k < D_DIM; ++k) {
      const float w = Wm[k*D_DIM + tid];
      #pragma unroll
      for (int r = 0; r < KB_RT; ++r) acc[r] += ysl[r][k] * w;
    }
    #pragma unroll
    for (int r = 0; r < KB_RT; ++r)
      vv_all[(size_t)(r0 + r)*D_DIM + tid] = acc[r];
  }
}

// ---------------- K3: dx -> softmax -> z_s -> p_t -> r_s -> c1 (ILP-unrolled) ----------------
__global__ __launch_bounds__(256, 6) void k_attn(
    const int* __restrict__ hist, const ushort* __restrict__ emb_h,
    const float* __restrict__ vv_all, const float* __restrict__ Ww,
    const float* __restrict__ bw, const float* __restrict__ Wt,
    float* __restrict__ rs_out, float* __restrict__ c1_out,
    float* __restrict__ rsinv_out)
{
  __shared__ int widx[L_LEN];
  __shared__ __align__(16) float ax[L_LEN];
  __shared__ __align__(16) float vvl[D_DIM];
  __shared__ float zs[D_DIM];
  __shared__ float ptile[160];
  __shared__ float red[40];
  const int r = blockIdx.x;
  const int tid = threadIdx.x, lane = tid & 63, wv = tid >> 6;

  if (tid < L_LEN) widx[tid] = hist[r*L_LEN + tid];
  if (tid < D_DIM) vvl[tid] = vv_all[(size_t)r*D_DIM + tid];
  __syncthreads();

  // dx[l] = e_w[l,:].v — wave-per-row, unroll-4 rows: 4 loads in flight,
  // 4 interleaved butterfly chains
  {
    float4 v4 = {0.f,0.f,0.f,0.f};
    if (lane < 50) v4 = *reinterpret_cast<const float4*>(vvl + 4*lane);
    const int lbase = wv*32;
    #pragma unroll
    for (int g = 0; g < 8; ++g) {
      const int l = lbase + g*4;
      float a0 = 0.f, a1 = 0.f, a2 = 0.f, a3 = 0.f;
      if (lane < 50) {
        const float4 e0 = unpack4(*reinterpret_cast<const uint2*>(emb_h + (size_t)widx[l  ]*D_DIM + 4*lane));
        const float4 e1 = unpack4(*reinterpret_cast<const uint2*>(emb_h + (size_t)widx[l+1]*D_DIM + 4*lane));
        const float4 e2 = unpack4(*reinterpret_cast<const uint2*>(emb_h + (size_t)widx[l+2]*D_DIM + 4*lane));
        const float4 e3 = unpack4(*reinterpret_cast<const uint2*>(emb_h + (size_t)widx[l+3]*D_DIM + 4*lane));
        a0 = e0.x*v4.x + e0.y*v4.y + e0.z*v4.z + e0.w*v4.w;
        a1 = e1.x*v4.x + e1.y*v4.y + e1.z*v4.z + e1.w*v4.w;
        a2 = e2.x*v4.x + e2.y*v4.y + e2.z*v4.z + e2.w*v4.w;
        a3 = e3.x*v4.x + e3.y*v4.y + e3.z*v4.z + e3.w*v4.w;
      }
      #pragma unroll
      for (int o = 32; o > 0; o >>= 1) {
        a0 += __shfl_xor(a0, o); a1 += __shfl_xor(a1, o);
        a2 += __shfl_xor(a2, o); a3 += __shfl_xor(a3, o);
      }
      if (lane == 0) { ax[l] = a0; ax[l+1] = a1; ax[l+2] = a2; ax[l+3] = a3; }
    }
  }
  __syncthreads();

  // softmax over 128 (wave0 reduces)
  if (tid < 64) {
    float m = fmaxf(ax[tid], ax[tid+64]);
    #pragma unroll
    for (int o = 32; o > 0; o >>= 1) m = fmaxf(m, __shfl_xor(m, o));
    if (tid == 0) red[0] = m;
  }
  __syncthreads();
  const float M = red[0];
  if (tid < L_LEN) ax[tid] = expf(ax[tid] - M);
  __syncthreads();
  if (tid < 64) {
    float s = ax[tid] + ax[tid+64];
    #pragma unroll
    for (int o = 32; o > 0; o >>= 1) s += __shfl_xor(s, o);
    if (tid == 0) red[1] = s;
  }
  __syncthreads();
  const float Sinv = 1.0f / red[1];
  if (tid < L_LEN) ax[tid] *= Sinv;
  __syncthreads();

  // z_s[d] = sum_i ax[i]*flat[128d+i]; half-wave per d, unroll-5 windows.
  // Every 4-half group is in-row & 8B-aligned (f ≡ 0 mod 4, row len 200 ≡ 0 mod 4).
  {
    const int lh = lane & 31;
    const int half = lane >> 5;
    const float4 ax4 = *reinterpret_cast<const float4*>(ax + 4*lh);
    const int dpb = wv*25;
    #pragma unroll
    for (int g = 0; g < 5; ++g) {
      const int dp0 = dpb + g*5;
      float a[5];
      #pragma unroll
      for (int j = 0; j < 5; ++j) {
        const int d = 2*(dp0 + j) + half;
        const int f = (d << 7) + 4*lh;
        const float4 e4 = unpack4(*reinterpret_cast<const uint2*>(
            emb_h + (size_t)widx[f/200]*D_DIM + (f % 200)));
        a[j] = e4.x*ax4.x + e4.y*ax4.y + e4.z*ax4.z + e4.w*ax4.w;
      }
      #pragma unroll
      for (int o = 16; o > 0; o >>= 1) {
        #pragma unroll
        for (int j = 0; j < 5; ++j) a[j] += __shfl_xor(a[j], o);
      }
      if (lh == 0) {
        #pragma unroll
        for (int j = 0; j < 5; ++j) zs[2*(dp0 + j) + half] = a[j];
      }
    }
  }
  __syncthreads();

  // p_t[a] = z_s . Ww[a,:] + bw[a]  — 8x20 partials
  if (tid < 160) {
    const int a = tid % 20, j = tid / 20;
    float s = 0.f;
    #pragma unroll
    for (int i = 0; i < 25; ++i) {
      const int d = j + 8*i;
      s += zs[d] * Ww[a*D_DIM + d];
    }
    ptile[tid] = s;
  }
  __syncthreads();
  if (tid < A_DIM) {
    float s = bw[tid];
    #pragma unroll
    for (int j = 0; j < 8; ++j) s += ptile[j*20 + tid];
    red[2 + tid] = s;
  }
  __syncthreads();

  // r_s[d] = sum_a p_t[a]*Wt[d,a]; norms for c1
  float rsd = 0.f, zsd = 0.f;
  if (tid < D_DIM) {
    float acc = 0.f;
    #pragma unroll
    for (int a = 0; a < A_DIM; ++a) acc += red[2+a] * Wt[tid*A_DIM + a];
    rsd = acc; zsd = zs[tid];
    rs_out[(size_t)r*D_DIM + tid] = acc;
  }
  float a0 = rsd*rsd, a1 = zsd*zsd, a2 = rsd*zsd;
  #pragma unroll
  for (int o = 32; o > 0; o >>= 1) {
    a0 += __shfl_xor(a0, o); a1 += __shfl_xor(a1, o); a2 += __shfl_xor(a2, o);
  }
  if ((tid & 63) == 0) { red[24+wv] = a0; red[28+wv] = a1; red[32+wv] = a2; }
  __syncthreads();
  if (tid == 0) {
    const float s0 = red[24]+red[25]+red[26]+red[27];
    const float s1 = red[28]+red[29]+red[30]+red[31];
    const float s2 = red[32]+red[33]+red[34]+red[35];
    const float nr = fmaxf(sqrtf(s0), EPS_);
    const float nz = fmaxf(sqrtf(s1), EPS_);
    c1_out[r] = s2 / (nr * nz);
    rsinv_out[r] = 1.0f / nr;
  }
}

// ---------------- K4: neg mean + c2 + margin loss; tail blocks do sparse bucketing ----------------
__global__ __launch_bounds__(256, 8) void k_neg(
    const int* __restrict__ neg, const ushort* __restrict__ emb_h,
    const float* __restrict__ rs, const float* __restrict__ c1,
    const float* __restrict__ rsinv, float* __restrict__ abae,
    const int* __restrict__ uidx, const float* __restrict__ uval,
    const int* __restrict__ iidx, const float* __restrict__ ival,
    int* __restrict__ cnt, int* __restrict__ scol, float* __restrict__ sval)
{
  const int s = blockIdx.x;
  const int tid = threadIdx.x, lane = tid & 63, wv = tid >> 6;

  if (s >= RN_TOT) {
    const int g = (s - RN_TOT)*256 + tid;
    if (g < NNZ_C) {
      const int b = uidx[g];
      const int slot = atomicAdd(&cnt[b], 1);
      if (slot < SLOT_CAP) {
        scol[b*SLOT_CAP + slot] = uidx[NNZ_C + g];
        sval[b*SLOT_CAP + slot] = uval[g];
      }
    } else {
      const int g2 = g - NNZ_C;
      const int b = iidx[g2];
      const int slot = atomicAdd(&cnt[B_SZ + b], 1);
      if (slot < SLOT_CAP) {
        scol[(B_SZ + b)*SLOT_CAP + slot] = iidx[NNZ_C + g2];
        sval[(B_SZ + b)*SLOT_CAP + slot] = ival[g2];
      }
    }
    return;
  }

  __shared__ int widx[L_LEN];
  __shared__ __align__(16) float part[4][D_DIM];
  __shared__ float red[8];
  const int rn = s;
  const int r = rn >> 1;               // NEG = 2
  if (tid < L_LEN) widx[tid] = neg[(size_t)rn*L_LEN + tid];
  __syncthreads();

  float4 a0 = {0,0,0,0}, a1 = {0,0,0,0}, a2 = {0,0,0,0}, a3 = {0,0,0,0};
  if (lane < 50) {
    const int l0 = wv*32;
    #pragma unroll
    for (int g = 0; g < 8; ++g) {
      const int l = l0 + g*4;
      const float4 v0 = unpack4(*reinterpret_cast<const uint2*>(emb_h + (size_t)widx[l  ]*D_DIM + 4*lane));
      const float4 v1 = unpack4(*reinterpret_cast<const uint2*>(emb_h + (size_t)widx[l+1]*D_DIM + 4*lane));
      const float4 v2 = unpack4(*reinterpret_cast<const uint2*>(emb_h + (size_t)widx[l+2]*D_DIM + 4*lane));
      const float4 v3 = unpack4(*reinterpret_cast<const uint2*>(emb_h + (size_t)widx[l+3]*D_DIM + 4*lane));
      a0.x += v0.x; a0.y += v0.y; a0.z += v0.z; a0.w += v0.w;
      a1.x += v1.x; a1.y += v1.y; a1.z += v1.z; a1.w += v1.w;
      a2.x += v2.x; a2.y += v2.y; a2.z += v2.z; a2.w += v2.w;
      a3.x += v3.x; a3.y += v3.y; a3.z += v3.z; a3.w += v3.w;
    }
    a0.x += a1.x + a2.x + a3.x; a0.y += a1.y + a2.y + a3.y;
    a0.z += a1.z + a2.z + a3.z; a0.w += a1.w + a2.w + a3.w;
    *reinterpret_cast<float4*>(&part[wv][4*lane]) = a0;
  }
  __syncthreads();

  float zn = 0.f, rsd = 0.f;
  if (tid < D_DIM) {
    zn = (part[0][tid] + part[1][tid] + part[2][tid] + part[3][tid]) * (1.0f/128.0f);
    rsd = rs[(size_t)r*D_DIM + tid];
  }
  float s0p = zn*zn, s1p = zn*rsd;
  #pragma unroll
  for (int o = 32; o > 0; o >>= 1) { s0p += __shfl_xor(s0p,o); s1p += __shfl_xor(s1p,o); }
  if ((tid & 63) == 0) { red[wv] = s0p; red[4+wv] = s1p; }
  __syncthreads();
  if (tid == 0) {
    const float s0 = red[0]+red[1]+red[2]+red[3];
    const float s1 = red[4]+red[5]+red[6]+red[7];
    const float nz = fmaxf(sqrtf(s0), EPS_);
    abae[rn] = fmaxf((s1/nz)*rsinv[r] - c1[r] + 1.0f, 0.0f);
  }
}

// ---------------- K5: merged segment-sum apply + FM (one block per b) ----------------
__global__ __launch_bounds__(512) void k_aggfm(
    const int* __restrict__ cnt, const int* __restrict__ scol,
    const float* __restrict__ sval, const float* __restrict__ rs,
    const float* __restrict__ fcw, const float* __restrict__ V,
    float* __restrict__ uae, float* __restrict__ iae,
    float* __restrict__ linb, float* __restrict__ quadb)
{
  __shared__ __align__(16) float ivec[2*D_DIM];
  __shared__ float redw[8];
  __shared__ float qpart[10];
  const int b = blockIdx.x;
  const int tid = threadIdx.x, lane = tid & 63, wv = tid >> 6;

  // phase A: user dims on waves 0-3 (tid<200), item dims on waves 4-7 (tid-256<200)
  if (tid < D_DIM) {
    int n = cnt[b]; n = n < SLOT_CAP ? n : SLOT_CAP;
    const int* cols = scol + (size_t)b*SLOT_CAP;
    const float* vals = sval + (size_t)b*SLOT_CAP;
    float acc = 0.f;
    for (int j = 0; j < n; ++j) acc += vals[j] * rs[(size_t)cols[j]*D_DIM + tid];
    ivec[tid] = acc;
    uae[(size_t)b*D_DIM + tid] = acc;
  } else if (tid >= 256 && tid < 256 + D_DIM) {
    const int t = tid - 256;
    int n = cnt[B_SZ + b]; n = n < SLOT_CAP ? n : SLOT_CAP;
    const int* cols = scol + (size_t)(B_SZ + b)*SLOT_CAP;
    const float* vals = sval + (size_t)(B_SZ + b)*SLOT_CAP;
    float acc = 0.f;
    for (int j = 0; j < n; ++j) acc += vals[j] * rs[(size_t)cols[j]*D_DIM + t];
    ivec[D_DIM + t] = acc;
    iae[(size_t)b*D_DIM + t] = acc;
  }
  __syncthreads();

  // phase B: linear term (400-dot) + quadratic partials (wave w -> k=w, +2 extra)
  float lv = 0.f;
  if (tid < 2*D_DIM) lv = ivec[tid] * fcw[tid];
  #pragma unroll
  for (int o = 32; o > 0; o >>= 1) lv += __shfl_xor(lv, o);
  if (lane == 0) redw[wv] = lv;

  {
    const int k = wv;
    float s1 = 0.f, s2 = 0.f;
    for (int f = lane; f < 2*D_DIM; f += 64) {
      const float x = ivec[f];
      const float vk = V[f*10 + k];
      s1 += x*vk; s2 += x*x*vk*vk;
    }
    #pragma unroll
    for (int o = 32; o > 0; o >>= 1) { s1 += __shfl_xor(s1,o); s2 += __shfl_xor(s2,o); }
    if (lane == 0) qpart[k] = s1*s1 - s2;
  }
  if (wv < 2) {
    const int k = 8 + wv;
    float s1 = 0.f, s2 = 0.f;
    for (int f = lane; f < 2*D_DIM; f += 64) {
      const float x = ivec[f];
      const float vk = V[f*10 + k];
      s1 += x*vk; s2 += x*x*vk*vk;
    }
    #pragma unroll
    for (int o = 32; o > 0; o >>= 1) { s1 += __shfl_xor(s1,o); s2 += __shfl_xor(s2,o); }
    if (lane == 0) qpart[k] = s1*s1 - s2;
  }
  __syncthreads();
  if (tid == 0) {
    float lin = 0.f;
    #pragma unroll
    for (int i = 0; i < 8; ++i) lin += redw[i];
    float q = 0.f;
    #pragma unroll
    for (int i = 0; i < 10; ++i) q += qpart[i];
    linb[b] = lin; quadb[b] = q;
  }
}

// ---------------- K6: fused quad-reduce + prediction + all final scalars ----------------
__global__ __launch_bounds__(1024) void k_final2(
    const float* __restrict__ quadb, const float* __restrict__ linb,
    const float* __restrict__ fcb, const int* __restrict__ user,
    const int* __restrict__ item, const float* __restrict__ busers,
    const float* __restrict__ bitems, const float* __restrict__ label,
    const float* __restrict__ Wt, const float* __restrict__ abae,
    float* __restrict__ pred, float* __restrict__ rl, float* __restrict__ obj)
{
  __shared__ float sA[16], sB[16], sC[16];
  __shared__ float cninv[A_DIM];
  __shared__ float quad_s;
  const int tid = threadIdx.x;
  const int lane = tid & 63;
  const int wv = tid >> 6;

  float q = quadb[tid];
  #pragma unroll
  for (int o = 32; o > 0; o >>= 1) q += __shfl_xor(q, o);
  if (lane == 0) sA[wv] = q;

  if (tid < A_DIM) {
    float s = 0.f;
    for (int d = 0; d < D_DIM; ++d) { const float w = Wt[d*A_DIM + tid]; s += w*w; }
    cninv[tid] = 1.0f / fmaxf(sqrtf(s), EPS_);
  }
  __syncthreads();
  if (wv == 0) {
    float s = (lane < 16) ? sA[lane] : 0.f;
    #pragma unroll
    for (int o = 32; o > 0; o >>= 1) s += __shfl_xor(s, o);
    if (lane == 0) quad_s = s;
  }
  __syncthreads();

  const float p = 0.5f*quad_s + linb[tid] + fcb[0]
                + busers[user[tid]] + bitems[item[tid]];
  pred[tid] = p;
  const float dd = p - label[tid];
  const float myrl = dd*dd;
  rl[tid] = myrl;

  float u = 0.f;
  if (tid < 400) {
    const int a = tid / 20, c = tid % 20;
    float dot = 0.f;
    for (int d = 0; d < D_DIM; ++d) dot += Wt[d*A_DIM + a]*Wt[d*A_DIM + c];
    const float g = dot*cninv[a]*cninv[c] - (a==c ? 1.0f : 0.0f);
    u = g*g;
  }
  float js = 0.f;
  #pragma unroll
  for (int j = 0; j < 8; ++j) js += abae[tid + 1024*j];
  float ms = myrl;

  #pragma unroll
  for (int o = 32; o > 0; o >>= 1) {
    u += __shfl_xor(u,o); js += __shfl_xor(js,o); ms += __shfl_xor(ms,o);
  }
  if (lane == 0) { sA[wv] = u; sB[wv] = js; sC[wv] = ms; }
  __syncthreads();
  if (tid == 0) {
    float U = 0.f, J = 0.f, Ms = 0.f;
    for (int i = 0; i < 16; ++i) { U += sA[i]; J += sB[i]; Ms += sC[i]; }
    obj[0] = Ms/1024.0f + 0.01f*(J/8192.0f) + 0.01f*(U/400.0f);
  }
}

extern "C" void kernel_launch(void* const* d_in, const int* in_sizes, int n_in,
                              void* d_out, int out_size, void* d_ws, size_t ws_size,
                              hipStream_t stream) {
  const int*   hist   = (const int*)  d_in[0];
  const int*   neg    = (const int*)  d_in[1];
  const int*   user   = (const int*)  d_in[2];
  const int*   item   = (const int*)  d_in[3];
  const float* label  = (const float*)d_in[4];
  const int*   uidx   = (const int*)  d_in[5];
  const float* uval   = (const float*)d_in[6];
  const int*   iidx   = (const int*)  d_in[7];
  const float* ival   = (const float*)d_in[8];
  const float* emb    = (const float*)d_in[9];
  const float* Wm     = (const float*)d_in[10];
  const float* Ww     = (const float*)d_in[11];
  const float* bw     = (const float*)d_in[12];
  const float* Wt     = (const float*)d_in[13];
  const float* fcw    = (const float*)d_in[14];
  const float* fcb    = (const float*)d_in[15];
  const float* V      = (const float*)d_in[16];
  const float* busers = (const float*)d_in[17];
  const float* bitems = (const float*)d_in[18];

  float* out  = (float*)d_out;
  float* obj  = out;                       // 1
  float* rl   = out + 1;                   // 1024
  float* abae = out + 1 + B_SZ;            // 8192
  float* pred = out + 1 + B_SZ + RN_TOT;   // 1024
  float* uae  = pred + B_SZ;               // 204800
  float* iae  = uae + (size_t)B_SZ*D_DIM;  // 204800

  float* ws     = (float*)d_ws;
  float* rs     = ws;                              // R*D
  float* ys_all = rs + (size_t)R_TOT*D_DIM;        // R*D
  float* vv_all = ys_all + (size_t)R_TOT*D_DIM;    // R*D
  float* c1     = vv_all + (size_t)R_TOT*D_DIM;    // R
  float* rsinv  = c1 + R_TOT;                      // R
  float* linb   = rsinv + R_TOT;                   // B
  float* quadb  = linb + B_SZ;                     // B
  float* sval   = quadb + B_SZ;                    // 2*B*SLOT_CAP floats
  int*   scol   = (int*)(sval + (size_t)2*B_SZ*SLOT_CAP);   // 2*B*SLOT_CAP ints
  int*   cnt    = scol + (size_t)2*B_SZ*SLOT_CAP;           // 2*B ints
  ushort* emb_h = (ushort*)(cnt + 2*B_SZ);                  // VOCAB*D halves

  const int cast_blocks = (VOCAB_C*D_DIM/4 + 255)/256;      // 6250

  k_cast    <<<cast_blocks, 256, 0, stream>>>(emb, emb_h, cnt);
  k_pos_mean<<<R_TOT, 256, 0, stream>>>(hist, emb_h, ys_all);
  k_matvec  <<<R_TOT/KB_RT, 256, 0, stream>>>(ys_all, Wm, vv_all);
  k_attn    <<<R_TOT, 256, 0, stream>>>(hist, emb_h, vv_all, Ww, bw, Wt, rs, c1, rsinv);
  k_neg     <<<RN_TOT + NBUCK_BLK, 256, 0, stream>>>(neg, emb_h, rs, c1, rsinv, abae,
                                                     uidx, uval, iidx, ival,
                                                     cnt, scol, sval);
  k_aggfm   <<<B_SZ, 512, 0, stream>>>(cnt, scol, sval, rs, fcw, V,
                                       uae, iae, linb, quadb);
  k_final2  <<<1, 1024, 0, stream>>>(quadb, linb, fcb, user, item, busers, bitems,
                                     label, Wt, abae, pred, rl, obj);
}